// Round 13
// baseline (231.467 us; speedup 1.0000x reference)
//
#include <hip/hip_runtime.h>

#define BLOCK 256
// R13: R12 body VERBATIM + __launch_bounds__(256, 4). Single-variable change.
// R12 diagnosis: occupancy recovered (63%) but VGPR_Count=24 -- the backend's
// default max-occupancy target squeezed the allocation so hard that only 1-2
// pk_fma accumulator chains fit in flight; VALUBusy pinned at ~50% = the
// single-chain ceiling (4cy latency / 2cy issue). Same signature in R3 (40
// VGPR, 48%) and R6 (40 VGPR, 41%): the ALLOCATOR, not the scheduler, is the
// binding constraint, which is why source-level interleaving (R6) was a no-op.
// Fix: declare 4 waves/SIMD sufficient -> 128-VGPR budget -> pre-RA scheduler
// can keep 4-8 independent jp-chains in flight. 31250 waves / (1024 SIMD x 4)
// = ~7.6 generations, still ample TLP for HBM latency.
// (R4's launch_bounds(256,4) failure was the 2.3KB alloca -> scratch, not the
// hint; R12's live set is ~25 v2f, safe.)
// Body: j-packed VOP3P, one row/thread. Weight pair {w[i][j],w[i][j+1]} is a
// contiguous u64 -> s_load_dwordx2 SGPR pair (legal VOP3P src). Input
// broadcast via op_sel on a legal 64-bit pair (HW-verified R10/R12):
//   fmaL: op_sel:[0,0,0] op_sel_hi:[0,1,1]   (src0.lo -> both halves)
//   fmaH: op_sel:[1,0,0] op_sel_hi:[1,1,1]   (src0.hi -> both halves)

typedef float v2f __attribute__((ext_vector_type(2)));
typedef unsigned long long u64;

struct WPtrs {
    const float* w[19];
    const float* b[19];
};

enum LId {FU1,FU2,KU1,KU2,HU1,HU2,MD1,MD2,MD3,HD1,HD2,KD1,KD2,HA1,HA2,KA1,KA2,FA1,FA2};

// acc.{lo,hi} += s.lo * w.{lo,hi}
__device__ __forceinline__ void fmaL(v2f& acc, const v2f s, const u64 w) {
    asm("v_pk_fma_f32 %0, %1, %2, %0 op_sel:[0,0,0] op_sel_hi:[0,1,1]"
        : "+v"(acc) : "v"(s), "s"(w));
}
// acc.{lo,hi} += s.hi * w.{lo,hi}
__device__ __forceinline__ void fmaH(v2f& acc, const v2f s, const u64 w) {
    asm("v_pk_fma_f32 %0, %1, %2, %0 op_sel:[1,0,0] op_sel_hi:[1,1,1]"
        : "+v"(acc) : "v"(s), "s"(w));
}
__device__ __forceinline__ v2f pkmax0(const v2f a) {
    const v2f z = {0.0f, 0.0f};
    return __builtin_elementwise_max(a, z);
}
__device__ __forceinline__ v2f bias2(const float* b, int jp) {
    return *reinterpret_cast<const v2f*>(b + 2*jp);   // 8B-aligned (jp even elems)
}

__global__ __launch_bounds__(BLOCK, 4) void pnet_kernel(
    const float* __restrict__ x, float* __restrict__ out, int B, WPtrs P) {
    const long long row = (long long)blockIdx.x * BLOCK + threadIdx.x;
    if (row >= B) return;

    // ---- load 11 features, pack into natural pairs ----
    const float* pr = x + row * 11;
    float xs[11];
#pragma unroll
    for (int c = 0; c < 11; ++c) xs[c] = pr[c];
    const v2f xp01 = {xs[0], xs[1]};
    const v2f xp23 = {xs[2], xs[3]};   // h = lo, k = hi
    const v2f xp45 = {xs[4], xs[5]};   // f = lo
    const v2f xp67 = {xs[6], xs[7]};
    const v2f xp89 = {xs[8], xs[9]};   // hd = lo, kd = hi
    const v2f xpA  = {xs[10], xs[10]}; // fd = lo

    // ---- fu1: [f, fd] -> 2 (1 jp) ----
    v2f fu1p;
    {
        const u64* wp = reinterpret_cast<const u64*>(P.w[FU1]);
        v2f a = bias2(P.b[FU1], 0);
        fmaL(a, xp45, wp[0]);          // f   * w[0][0..1]
        fmaL(a, xpA,  wp[1]);          // fd  * w[1][0..1]
        fu1p = pkmax0(a);
    }
    // ---- fu2: 2 -> 2 ----
    v2f fup;
    {
        const u64* wp = reinterpret_cast<const u64*>(P.w[FU2]);
        v2f a = bias2(P.b[FU2], 0);
        fmaL(a, fu1p, wp[0]);
        fmaH(a, fu1p, wp[1]);
        fup = pkmax0(a);
    }

    // ---- ku1: [k, kd, f_up(2)] -> 4 (2 jp), idx = i*2+jp ----
    v2f ku1p[2];
    {
        const u64* wp = reinterpret_cast<const u64*>(P.w[KU1]);
#pragma unroll
        for (int jp = 0; jp < 2; ++jp) {
            v2f a = bias2(P.b[KU1], jp);
            fmaH(a, xp23, wp[0*2+jp]);     // k
            fmaH(a, xp89, wp[1*2+jp]);     // kd
            fmaL(a, fup,  wp[2*2+jp]);
            fmaH(a, fup,  wp[3*2+jp]);
            ku1p[jp] = pkmax0(a);
        }
    }
    // ---- ku2: 4 -> 4 ----
    v2f kup[2];
    {
        const u64* wp = reinterpret_cast<const u64*>(P.w[KU2]);
#pragma unroll
        for (int jp = 0; jp < 2; ++jp) {
            v2f a = bias2(P.b[KU2], jp);
            fmaL(a, ku1p[0], wp[0*2+jp]);
            fmaH(a, ku1p[0], wp[1*2+jp]);
            fmaL(a, ku1p[1], wp[2*2+jp]);
            fmaH(a, ku1p[1], wp[3*2+jp]);
            kup[jp] = pkmax0(a);
        }
    }

    // ---- hu1: [h, hd, k_up(4)] -> 6 (3 jp), idx = i*3+jp ----
    v2f hu1p[3];
    {
        const u64* wp = reinterpret_cast<const u64*>(P.w[HU1]);
#pragma unroll
        for (int jp = 0; jp < 3; ++jp) {
            v2f a = bias2(P.b[HU1], jp);
            fmaL(a, xp23,   wp[0*3+jp]);   // h
            fmaL(a, xp89,   wp[1*3+jp]);   // hd
            fmaL(a, kup[0], wp[2*3+jp]);
            fmaH(a, kup[0], wp[3*3+jp]);
            fmaL(a, kup[1], wp[4*3+jp]);
            fmaH(a, kup[1], wp[5*3+jp]);
            hu1p[jp] = pkmax0(a);
        }
    }
    // ---- hu2: 6 -> 6 ----
    v2f hup[3];
    {
        const u64* wp = reinterpret_cast<const u64*>(P.w[HU2]);
#pragma unroll
        for (int jp = 0; jp < 3; ++jp) {
            v2f a = bias2(P.b[HU2], jp);
            fmaL(a, hu1p[0], wp[0*3+jp]);
            fmaH(a, hu1p[0], wp[1*3+jp]);
            fmaL(a, hu1p[1], wp[2*3+jp]);
            fmaH(a, hu1p[1], wp[3*3+jp]);
            fmaL(a, hu1p[2], wp[4*3+jp]);
            fmaH(a, hu1p[2], wp[5*3+jp]);
            hup[jp] = pkmax0(a);
        }
    }

    // ---- md1: [x0,x1,x5,x6,x7, h_up(6)] -> 16 (8 jp), idx = i*8+jp ----
    v2f m1[8];
    {
        const u64* wp = reinterpret_cast<const u64*>(P.w[MD1]);
#pragma unroll
        for (int jp = 0; jp < 8; ++jp) {
            v2f a = bias2(P.b[MD1], jp);
            fmaL(a, xp01,   wp[0*8+jp]);   // x0
            fmaH(a, xp01,   wp[1*8+jp]);   // x1
            fmaH(a, xp45,   wp[2*8+jp]);   // x5
            fmaL(a, xp67,   wp[3*8+jp]);   // x6
            fmaH(a, xp67,   wp[4*8+jp]);   // x7
            fmaL(a, hup[0], wp[5*8+jp]);
            fmaH(a, hup[0], wp[6*8+jp]);
            fmaL(a, hup[1], wp[7*8+jp]);
            fmaH(a, hup[1], wp[8*8+jp]);
            fmaL(a, hup[2], wp[9*8+jp]);
            fmaH(a, hup[2], wp[10*8+jp]);
            m1[jp] = pkmax0(a);
        }
    }
    // ---- md2: 16 -> 16 (8 jp) ----
    v2f m2[8];
    {
        const u64* wp = reinterpret_cast<const u64*>(P.w[MD2]);
#pragma unroll
        for (int jp = 0; jp < 8; ++jp) {
            v2f a = bias2(P.b[MD2], jp);
#pragma unroll
            for (int p = 0; p < 8; ++p) {
                fmaL(a, m1[p], wp[(2*p)  *8+jp]);
                fmaH(a, m1[p], wp[(2*p+1)*8+jp]);
            }
            m2[jp] = pkmax0(a);
        }
    }
    // ---- md3: 16 -> 6 (3 jp), idx = i*3+jp ----
    v2f m3[3];
    {
        const u64* wp = reinterpret_cast<const u64*>(P.w[MD3]);
#pragma unroll
        for (int jp = 0; jp < 3; ++jp) {
            v2f a = bias2(P.b[MD3], jp);
#pragma unroll
            for (int p = 0; p < 8; ++p) {
                fmaL(a, m2[p], wp[(2*p)  *3+jp]);
                fmaH(a, m2[p], wp[(2*p+1)*3+jp]);
            }
            m3[jp] = pkmax0(a);
        }
    }

    // ---- hd1: 6 -> 4 (2 jp), idx = i*2+jp ----
    v2f d1[2];
    {
        const u64* wp = reinterpret_cast<const u64*>(P.w[HD1]);
#pragma unroll
        for (int jp = 0; jp < 2; ++jp) {
            v2f a = bias2(P.b[HD1], jp);
            fmaL(a, m3[0], wp[0*2+jp]);
            fmaH(a, m3[0], wp[1*2+jp]);
            fmaL(a, m3[1], wp[2*2+jp]);
            fmaH(a, m3[1], wp[3*2+jp]);
            fmaL(a, m3[2], wp[4*2+jp]);
            fmaH(a, m3[2], wp[5*2+jp]);
            d1[jp] = pkmax0(a);
        }
    }
    // ---- hd2: 4 -> 4 (2 jp) ----
    v2f d2[2];
    {
        const u64* wp = reinterpret_cast<const u64*>(P.w[HD2]);
#pragma unroll
        for (int jp = 0; jp < 2; ++jp) {
            v2f a = bias2(P.b[HD2], jp);
            fmaL(a, d1[0], wp[0*2+jp]);
            fmaH(a, d1[0], wp[1*2+jp]);
            fmaL(a, d1[1], wp[2*2+jp]);
            fmaH(a, d1[1], wp[3*2+jp]);
            d2[jp] = pkmax0(a);
        }
    }

    // ---- kd1: 4 -> 2 (1 jp) ----
    v2f e1;
    {
        const u64* wp = reinterpret_cast<const u64*>(P.w[KD1]);
        v2f a = bias2(P.b[KD1], 0);
        fmaL(a, d2[0], wp[0]);
        fmaH(a, d2[0], wp[1]);
        fmaL(a, d2[1], wp[2]);
        fmaH(a, d2[1], wp[3]);
        e1 = pkmax0(a);
    }
    // ---- kd2: 2 -> 2 ----
    v2f e2;
    {
        const u64* wp = reinterpret_cast<const u64*>(P.w[KD2]);
        v2f a = bias2(P.b[KD2], 0);
        fmaL(a, e1, wp[0]);
        fmaH(a, e1, wp[1]);
        e2 = pkmax0(a);
    }

    // ---- ha1: [h, hd, m_down(6)] -> 4 (2 jp), idx = i*2+jp ----
    v2f g[2];
    {
        const u64* wp = reinterpret_cast<const u64*>(P.w[HA1]);
#pragma unroll
        for (int jp = 0; jp < 2; ++jp) {
            v2f a = bias2(P.b[HA1], jp);
            fmaL(a, xp23,  wp[0*2+jp]);    // h
            fmaL(a, xp89,  wp[1*2+jp]);    // hd
            fmaL(a, m3[0], wp[2*2+jp]);
            fmaH(a, m3[0], wp[3*2+jp]);
            fmaL(a, m3[1], wp[4*2+jp]);
            fmaH(a, m3[1], wp[5*2+jp]);
            fmaL(a, m3[2], wp[6*2+jp]);
            fmaH(a, m3[2], wp[7*2+jp]);
            g[jp] = pkmax0(a);
        }
    }
    // ---- ha2: 4 -> 1 (scalar head) ----
    const float* wha = P.w[HA2];
    float h_act = P.b[HA2][0];
    h_act = __builtin_fmaf(g[0].x, wha[0], h_act);
    h_act = __builtin_fmaf(g[0].y, wha[1], h_act);
    h_act = __builtin_fmaf(g[1].x, wha[2], h_act);
    h_act = __builtin_fmaf(g[1].y, wha[3], h_act);

    // ---- ka1: [k, kd, h_down(4)] -> 4 (2 jp) ----
    v2f q[2];
    {
        const u64* wp = reinterpret_cast<const u64*>(P.w[KA1]);
#pragma unroll
        for (int jp = 0; jp < 2; ++jp) {
            v2f a = bias2(P.b[KA1], jp);
            fmaH(a, xp23,  wp[0*2+jp]);    // k
            fmaH(a, xp89,  wp[1*2+jp]);    // kd
            fmaL(a, d2[0], wp[2*2+jp]);
            fmaH(a, d2[0], wp[3*2+jp]);
            fmaL(a, d2[1], wp[4*2+jp]);
            fmaH(a, d2[1], wp[5*2+jp]);
            q[jp] = pkmax0(a);
        }
    }
    // ---- ka2: 4 -> 1 ----
    const float* wka = P.w[KA2];
    float k_act = P.b[KA2][0];
    k_act = __builtin_fmaf(q[0].x, wka[0], k_act);
    k_act = __builtin_fmaf(q[0].y, wka[1], k_act);
    k_act = __builtin_fmaf(q[1].x, wka[2], k_act);
    k_act = __builtin_fmaf(q[1].y, wka[3], k_act);

    // ---- fa1: [f, fd, k_down(2)] -> 4 (2 jp) ----
    v2f r[2];
    {
        const u64* wp = reinterpret_cast<const u64*>(P.w[FA1]);
#pragma unroll
        for (int jp = 0; jp < 2; ++jp) {
            v2f a = bias2(P.b[FA1], jp);
            fmaL(a, xp45, wp[0*2+jp]);     // f
            fmaL(a, xpA,  wp[1*2+jp]);     // fd
            fmaL(a, e2,   wp[2*2+jp]);
            fmaH(a, e2,   wp[3*2+jp]);
            r[jp] = pkmax0(a);
        }
    }
    // ---- fa2: 4 -> 1 ----
    const float* wfa = P.w[FA2];
    float f_act = P.b[FA2][0];
    f_act = __builtin_fmaf(r[0].x, wfa[0], f_act);
    f_act = __builtin_fmaf(r[0].y, wfa[1], f_act);
    f_act = __builtin_fmaf(r[1].x, wfa[2], f_act);
    f_act = __builtin_fmaf(r[1].y, wfa[3], f_act);

    // ---- store ----
    float* po = out + row * 3;
    po[0] = h_act;
    po[1] = f_act;
    po[2] = k_act;
}

extern "C" void kernel_launch(void* const* d_in, const int* in_sizes, int n_in,
                              void* d_out, int out_size, void* d_ws, size_t ws_size,
                              hipStream_t stream) {
    const float* x = (const float*)d_in[0];
    float* out = (float*)d_out;
    const int B = in_sizes[0] / 11;

    WPtrs P;
    for (int i = 0; i < 19; ++i) {
        P.w[i] = (const float*)d_in[1 + 2*i];
        P.b[i] = (const float*)d_in[2 + 2*i];
    }

    const int blocks = (int)(((long long)B + BLOCK - 1) / BLOCK);
    pnet_kernel<<<blocks, BLOCK, 0, stream>>>(x, out, B, P);
}

// Round 14
// 229.629 us; speedup vs baseline: 1.0080x; 1.0080x over previous
//
#include <hip/hip_runtime.h>

#define BLOCK 256
// R14: R12 body + vectorized input loads. Single-variable change.
// Ledger model (fits R0/R9/R10/R12): SIMD ISSUE pipe is the binding resource
// (wave64 VALU = 2 issue-cyc; per-wave wall ~= resident x own-issue). R9's
// +865 ds_reads cost exactly the predicted issue time; R10's s_load sharing
// across 2 rows gained nothing per-row; only instruction-count reductions
// have ever moved dur (900->470 insts = 67->60us). R13's launch_bounds(256,4)
// was a no-op (VGPR stayed 24).
// Trim here: input path 23 insts -> 6. The j-packed pairs are CONTIGUOUS in
// the row: {x0,x1},{x2,x3},{x4,x5},{x6,x7},{x8,x9} = 5 global_load_dwordx2,
// and x10 rides an OVERLAPPING pair {x9,x10} consumed via fmaH (broadcast-hi)
// -- zero packing movs, zero splat. Input L2 transactions/wave 484 -> 264.
// (Odd rows -> 4B-aligned dwordx2: legal for gfx9 global loads.)
// Body: j-packed VOP3P, one row/thread, weight pair {w[i][j],w[i][j+1]} as
// contiguous u64 -> s_load_dwordx2 SGPR pair (legal VOP3P src; R7: lone
// 32-bit SGPR is not). op_sel broadcast (HW-verified R10/R12):
//   fmaL: op_sel:[0,0,0] op_sel_hi:[0,1,1]   (src0.lo -> both halves)
//   fmaH: op_sel:[1,0,0] op_sel_hi:[1,1,1]   (src0.hi -> both halves)

typedef float v2f __attribute__((ext_vector_type(2)));
typedef unsigned long long u64;

struct WPtrs {
    const float* w[19];
    const float* b[19];
};

enum LId {FU1,FU2,KU1,KU2,HU1,HU2,MD1,MD2,MD3,HD1,HD2,KD1,KD2,HA1,HA2,KA1,KA2,FA1,FA2};

// acc.{lo,hi} += s.lo * w.{lo,hi}
__device__ __forceinline__ void fmaL(v2f& acc, const v2f s, const u64 w) {
    asm("v_pk_fma_f32 %0, %1, %2, %0 op_sel:[0,0,0] op_sel_hi:[0,1,1]"
        : "+v"(acc) : "v"(s), "s"(w));
}
// acc.{lo,hi} += s.hi * w.{lo,hi}
__device__ __forceinline__ void fmaH(v2f& acc, const v2f s, const u64 w) {
    asm("v_pk_fma_f32 %0, %1, %2, %0 op_sel:[1,0,0] op_sel_hi:[1,1,1]"
        : "+v"(acc) : "v"(s), "s"(w));
}
__device__ __forceinline__ v2f pkmax0(const v2f a) {
    const v2f z = {0.0f, 0.0f};
    return __builtin_elementwise_max(a, z);
}
__device__ __forceinline__ v2f bias2(const float* b, int jp) {
    return *reinterpret_cast<const v2f*>(b + 2*jp);   // 8B-aligned (jp even elems)
}

__global__ __launch_bounds__(BLOCK) void pnet_kernel(
    const float* __restrict__ x, float* __restrict__ out, int B, WPtrs P) {
    const long long row = (long long)blockIdx.x * BLOCK + threadIdx.x;
    if (row >= B) return;

    // ---- load 11 features as 6 overlapping v2f pairs (no packing movs) ----
    const float* pr = x + row * 11;
    const v2f xp01 = *reinterpret_cast<const v2f*>(pr + 0);  // {x0,x1}
    const v2f xp23 = *reinterpret_cast<const v2f*>(pr + 2);  // {h,  k }
    const v2f xp45 = *reinterpret_cast<const v2f*>(pr + 4);  // {f,  x5}
    const v2f xp67 = *reinterpret_cast<const v2f*>(pr + 6);  // {x6, x7}
    const v2f xp89 = *reinterpret_cast<const v2f*>(pr + 8);  // {hd, kd}
    const v2f xp9A = *reinterpret_cast<const v2f*>(pr + 9);  // {kd, fd}  fd = hi

    // ---- fu1: [f, fd] -> 2 (1 jp) ----
    v2f fu1p;
    {
        const u64* wp = reinterpret_cast<const u64*>(P.w[FU1]);
        v2f a = bias2(P.b[FU1], 0);
        fmaL(a, xp45, wp[0]);          // f   * w[0][0..1]
        fmaH(a, xp9A, wp[1]);          // fd  * w[1][0..1]
        fu1p = pkmax0(a);
    }
    // ---- fu2: 2 -> 2 ----
    v2f fup;
    {
        const u64* wp = reinterpret_cast<const u64*>(P.w[FU2]);
        v2f a = bias2(P.b[FU2], 0);
        fmaL(a, fu1p, wp[0]);
        fmaH(a, fu1p, wp[1]);
        fup = pkmax0(a);
    }

    // ---- ku1: [k, kd, f_up(2)] -> 4 (2 jp), idx = i*2+jp ----
    v2f ku1p[2];
    {
        const u64* wp = reinterpret_cast<const u64*>(P.w[KU1]);
#pragma unroll
        for (int jp = 0; jp < 2; ++jp) {
            v2f a = bias2(P.b[KU1], jp);
            fmaH(a, xp23, wp[0*2+jp]);     // k
            fmaH(a, xp89, wp[1*2+jp]);     // kd
            fmaL(a, fup,  wp[2*2+jp]);
            fmaH(a, fup,  wp[3*2+jp]);
            ku1p[jp] = pkmax0(a);
        }
    }
    // ---- ku2: 4 -> 4 ----
    v2f kup[2];
    {
        const u64* wp = reinterpret_cast<const u64*>(P.w[KU2]);
#pragma unroll
        for (int jp = 0; jp < 2; ++jp) {
            v2f a = bias2(P.b[KU2], jp);
            fmaL(a, ku1p[0], wp[0*2+jp]);
            fmaH(a, ku1p[0], wp[1*2+jp]);
            fmaL(a, ku1p[1], wp[2*2+jp]);
            fmaH(a, ku1p[1], wp[3*2+jp]);
            kup[jp] = pkmax0(a);
        }
    }

    // ---- hu1: [h, hd, k_up(4)] -> 6 (3 jp), idx = i*3+jp ----
    v2f hu1p[3];
    {
        const u64* wp = reinterpret_cast<const u64*>(P.w[HU1]);
#pragma unroll
        for (int jp = 0; jp < 3; ++jp) {
            v2f a = bias2(P.b[HU1], jp);
            fmaL(a, xp23,   wp[0*3+jp]);   // h
            fmaL(a, xp89,   wp[1*3+jp]);   // hd
            fmaL(a, kup[0], wp[2*3+jp]);
            fmaH(a, kup[0], wp[3*3+jp]);
            fmaL(a, kup[1], wp[4*3+jp]);
            fmaH(a, kup[1], wp[5*3+jp]);
            hu1p[jp] = pkmax0(a);
        }
    }
    // ---- hu2: 6 -> 6 ----
    v2f hup[3];
    {
        const u64* wp = reinterpret_cast<const u64*>(P.w[HU2]);
#pragma unroll
        for (int jp = 0; jp < 3; ++jp) {
            v2f a = bias2(P.b[HU2], jp);
            fmaL(a, hu1p[0], wp[0*3+jp]);
            fmaH(a, hu1p[0], wp[1*3+jp]);
            fmaL(a, hu1p[1], wp[2*3+jp]);
            fmaH(a, hu1p[1], wp[3*3+jp]);
            fmaL(a, hu1p[2], wp[4*3+jp]);
            fmaH(a, hu1p[2], wp[5*3+jp]);
            hup[jp] = pkmax0(a);
        }
    }

    // ---- md1: [x0,x1,x5,x6,x7, h_up(6)] -> 16 (8 jp), idx = i*8+jp ----
    v2f m1[8];
    {
        const u64* wp = reinterpret_cast<const u64*>(P.w[MD1]);
#pragma unroll
        for (int jp = 0; jp < 8; ++jp) {
            v2f a = bias2(P.b[MD1], jp);
            fmaL(a, xp01,   wp[0*8+jp]);   // x0
            fmaH(a, xp01,   wp[1*8+jp]);   // x1
            fmaH(a, xp45,   wp[2*8+jp]);   // x5
            fmaL(a, xp67,   wp[3*8+jp]);   // x6
            fmaH(a, xp67,   wp[4*8+jp]);   // x7
            fmaL(a, hup[0], wp[5*8+jp]);
            fmaH(a, hup[0], wp[6*8+jp]);
            fmaL(a, hup[1], wp[7*8+jp]);
            fmaH(a, hup[1], wp[8*8+jp]);
            fmaL(a, hup[2], wp[9*8+jp]);
            fmaH(a, hup[2], wp[10*8+jp]);
            m1[jp] = pkmax0(a);
        }
    }
    // ---- md2: 16 -> 16 (8 jp) ----
    v2f m2[8];
    {
        const u64* wp = reinterpret_cast<const u64*>(P.w[MD2]);
#pragma unroll
        for (int jp = 0; jp < 8; ++jp) {
            v2f a = bias2(P.b[MD2], jp);
#pragma unroll
            for (int p = 0; p < 8; ++p) {
                fmaL(a, m1[p], wp[(2*p)  *8+jp]);
                fmaH(a, m1[p], wp[(2*p+1)*8+jp]);
            }
            m2[jp] = pkmax0(a);
        }
    }
    // ---- md3: 16 -> 6 (3 jp), idx = i*3+jp ----
    v2f m3[3];
    {
        const u64* wp = reinterpret_cast<const u64*>(P.w[MD3]);
#pragma unroll
        for (int jp = 0; jp < 3; ++jp) {
            v2f a = bias2(P.b[MD3], jp);
#pragma unroll
            for (int p = 0; p < 8; ++p) {
                fmaL(a, m2[p], wp[(2*p)  *3+jp]);
                fmaH(a, m2[p], wp[(2*p+1)*3+jp]);
            }
            m3[jp] = pkmax0(a);
        }
    }

    // ---- hd1: 6 -> 4 (2 jp), idx = i*2+jp ----
    v2f d1[2];
    {
        const u64* wp = reinterpret_cast<const u64*>(P.w[HD1]);
#pragma unroll
        for (int jp = 0; jp < 2; ++jp) {
            v2f a = bias2(P.b[HD1], jp);
            fmaL(a, m3[0], wp[0*2+jp]);
            fmaH(a, m3[0], wp[1*2+jp]);
            fmaL(a, m3[1], wp[2*2+jp]);
            fmaH(a, m3[1], wp[3*2+jp]);
            fmaL(a, m3[2], wp[4*2+jp]);
            fmaH(a, m3[2], wp[5*2+jp]);
            d1[jp] = pkmax0(a);
        }
    }
    // ---- hd2: 4 -> 4 (2 jp) ----
    v2f d2[2];
    {
        const u64* wp = reinterpret_cast<const u64*>(P.w[HD2]);
#pragma unroll
        for (int jp = 0; jp < 2; ++jp) {
            v2f a = bias2(P.b[HD2], jp);
            fmaL(a, d1[0], wp[0*2+jp]);
            fmaH(a, d1[0], wp[1*2+jp]);
            fmaL(a, d1[1], wp[2*2+jp]);
            fmaH(a, d1[1], wp[3*2+jp]);
            d2[jp] = pkmax0(a);
        }
    }

    // ---- kd1: 4 -> 2 (1 jp) ----
    v2f e1;
    {
        const u64* wp = reinterpret_cast<const u64*>(P.w[KD1]);
        v2f a = bias2(P.b[KD1], 0);
        fmaL(a, d2[0], wp[0]);
        fmaH(a, d2[0], wp[1]);
        fmaL(a, d2[1], wp[2]);
        fmaH(a, d2[1], wp[3]);
        e1 = pkmax0(a);
    }
    // ---- kd2: 2 -> 2 ----
    v2f e2;
    {
        const u64* wp = reinterpret_cast<const u64*>(P.w[KD2]);
        v2f a = bias2(P.b[KD2], 0);
        fmaL(a, e1, wp[0]);
        fmaH(a, e1, wp[1]);
        e2 = pkmax0(a);
    }

    // ---- ha1: [h, hd, m_down(6)] -> 4 (2 jp), idx = i*2+jp ----
    v2f g[2];
    {
        const u64* wp = reinterpret_cast<const u64*>(P.w[HA1]);
#pragma unroll
        for (int jp = 0; jp < 2; ++jp) {
            v2f a = bias2(P.b[HA1], jp);
            fmaL(a, xp23,  wp[0*2+jp]);    // h
            fmaL(a, xp89,  wp[1*2+jp]);    // hd
            fmaL(a, m3[0], wp[2*2+jp]);
            fmaH(a, m3[0], wp[3*2+jp]);
            fmaL(a, m3[1], wp[4*2+jp]);
            fmaH(a, m3[1], wp[5*2+jp]);
            fmaL(a, m3[2], wp[6*2+jp]);
            fmaH(a, m3[2], wp[7*2+jp]);
            g[jp] = pkmax0(a);
        }
    }
    // ---- ha2: 4 -> 1 (scalar head) ----
    const float* wha = P.w[HA2];
    float h_act = P.b[HA2][0];
    h_act = __builtin_fmaf(g[0].x, wha[0], h_act);
    h_act = __builtin_fmaf(g[0].y, wha[1], h_act);
    h_act = __builtin_fmaf(g[1].x, wha[2], h_act);
    h_act = __builtin_fmaf(g[1].y, wha[3], h_act);

    // ---- ka1: [k, kd, h_down(4)] -> 4 (2 jp) ----
    v2f q[2];
    {
        const u64* wp = reinterpret_cast<const u64*>(P.w[KA1]);
#pragma unroll
        for (int jp = 0; jp < 2; ++jp) {
            v2f a = bias2(P.b[KA1], jp);
            fmaH(a, xp23,  wp[0*2+jp]);    // k
            fmaH(a, xp89,  wp[1*2+jp]);    // kd
            fmaL(a, d2[0], wp[2*2+jp]);
            fmaH(a, d2[0], wp[3*2+jp]);
            fmaL(a, d2[1], wp[4*2+jp]);
            fmaH(a, d2[1], wp[5*2+jp]);
            q[jp] = pkmax0(a);
        }
    }
    // ---- ka2: 4 -> 1 ----
    const float* wka = P.w[KA2];
    float k_act = P.b[KA2][0];
    k_act = __builtin_fmaf(q[0].x, wka[0], k_act);
    k_act = __builtin_fmaf(q[0].y, wka[1], k_act);
    k_act = __builtin_fmaf(q[1].x, wka[2], k_act);
    k_act = __builtin_fmaf(q[1].y, wka[3], k_act);

    // ---- fa1: [f, fd, k_down(2)] -> 4 (2 jp) ----
    v2f r[2];
    {
        const u64* wp = reinterpret_cast<const u64*>(P.w[FA1]);
#pragma unroll
        for (int jp = 0; jp < 2; ++jp) {
            v2f a = bias2(P.b[FA1], jp);
            fmaL(a, xp45, wp[0*2+jp]);     // f
            fmaH(a, xp9A, wp[1*2+jp]);     // fd (hi of {x9,x10})
            fmaL(a, e2,   wp[2*2+jp]);
            fmaH(a, e2,   wp[3*2+jp]);
            r[jp] = pkmax0(a);
        }
    }
    // ---- fa2: 4 -> 1 ----
    const float* wfa = P.w[FA2];
    float f_act = P.b[FA2][0];
    f_act = __builtin_fmaf(r[0].x, wfa[0], f_act);
    f_act = __builtin_fmaf(r[0].y, wfa[1], f_act);
    f_act = __builtin_fmaf(r[1].x, wfa[2], f_act);
    f_act = __builtin_fmaf(r[1].y, wfa[3], f_act);

    // ---- store ----
    float* po = out + row * 3;
    po[0] = h_act;
    po[1] = f_act;
    po[2] = k_act;
}

extern "C" void kernel_launch(void* const* d_in, const int* in_sizes, int n_in,
                              void* d_out, int out_size, void* d_ws, size_t ws_size,
                              hipStream_t stream) {
    const float* x = (const float*)d_in[0];
    float* out = (float*)d_out;
    const int B = in_sizes[0] / 11;

    WPtrs P;
    for (int i = 0; i < 19; ++i) {
        P.w[i] = (const float*)d_in[1 + 2*i];
        P.b[i] = (const float*)d_in[2 + 2*i];
    }

    const int blocks = (int)(((long long)B + BLOCK - 1) / BLOCK);
    pnet_kernel<<<blocks, BLOCK, 0, stream>>>(x, out, B, P);
}

// Round 15
// 224.565 us; speedup vs baseline: 1.0307x; 1.0226x over previous
//
#include <hip/hip_runtime.h>

#define BLOCK 256
// R15: R14 body + SEQUENTIAL WEIGHT STREAM. Single-variable change.
// Ledger: issue is ~25% of wall (2x-inflated VALUBusy corrected); the ~45us
// stall survived ILP, input coalescing, LDS weights, persistence, occupancy,
// and inst trimming. Last untouched structure: weights come from 38 separate
// arg pointers, and md-layer u64 reads are 128B-strided -> ~450 discrete
// s_load_dwordx2/wave, non-mergeable, SGPR-limited lookahead, lgkmcnt wait
// per chunk. Fix: prep writes ALL weights+biases into d_ws as ONE 3.5KB
// stream in EXACT consumption order (per jp: [bias pair, w-pair per fma]).
// Kernel reads W[base + constexpr] sequentially -> compiler merges into
// s_load_dwordx8/x16 runs (~8x fewer SMEM ops), prefetches deep, and the 38
// arg-pointer loads collapse to 1.
// Body: j-packed VOP3P, 1 row/thread, vectorized input loads (R14).
//   fmaL: op_sel:[0,0,0] op_sel_hi:[0,1,1]   (src0.lo -> both halves)
//   fmaH: op_sel:[1,0,0] op_sel_hi:[1,1,1]   (src0.hi -> both halves)
// (HW-verified R10/R12/R14; R7: a lone 32-bit SGPR is not a legal VOP3P src.)

typedef float v2f __attribute__((ext_vector_type(2)));
typedef unsigned long long u64;

struct WPtrs {
    const float* w[19];
    const float* b[19];
};

// layer params and u64 offsets of each layer block in the stream.
// packed layer size = (DOUT/2)*(1+DIN); head (DOUT=1) = 3 u64 [b,w0..3,pad].
__constant__ const int kDIN[19]  = {2,2,4,4,6,6,11,16,16,6,4,4,2,8,4,6,4,4,4};
__constant__ const int kDOUT[19] = {2,2,4,4,6,6,16,16,6,4,4,2,2,4,1,4,1,4,1};
__constant__ const int kOFF[19]  = {0,3,6,16,26,47,68,164,300,351,365,375,380,383,401,404,418,421,431};
// total stream: 434 u64 = 3472 B

// ---- prep: write the consumption-ordered stream into d_ws ----
__global__ void prep_kernel(WPtrs P, float* __restrict__ ws) {
    const int l = blockIdx.x;
    const int t = threadIdx.x;
    const int din = kDIN[l], dout = kDOUT[l];
    const int off = kOFF[l];
    if (dout == 1) {                       // head: [b, w0..w3, pad]
        if (t == 0) {
            float* d = ws + 2*off;
            d[0] = P.b[l][0];
            for (int i = 0; i < 4; ++i) d[1+i] = P.w[l][i];
            d[5] = 0.0f;
        }
        return;
    }
    const int pairs  = dout >> 1;
    const int stride = 1 + din;            // u64 per jp block
    for (int jp = t; jp < pairs; jp += blockDim.x) {
        float* d = ws + 2*(off + jp*stride);
        d[0] = P.b[l][2*jp];
        d[1] = P.b[l][2*jp + 1];
        for (int i = 0; i < din; ++i) {
            d[2 + 2*i] = P.w[l][i*dout + 2*jp];
            d[3 + 2*i] = P.w[l][i*dout + 2*jp + 1];
        }
    }
}

// acc.{lo,hi} += s.lo * w.{lo,hi}
__device__ __forceinline__ void fmaL(v2f& acc, const v2f s, const u64 w) {
    asm("v_pk_fma_f32 %0, %1, %2, %0 op_sel:[0,0,0] op_sel_hi:[0,1,1]"
        : "+v"(acc) : "v"(s), "s"(w));
}
// acc.{lo,hi} += s.hi * w.{lo,hi}
__device__ __forceinline__ void fmaH(v2f& acc, const v2f s, const u64 w) {
    asm("v_pk_fma_f32 %0, %1, %2, %0 op_sel:[1,0,0] op_sel_hi:[1,1,1]"
        : "+v"(acc) : "v"(s), "s"(w));
}
__device__ __forceinline__ v2f pkmax0(const v2f a) {
    const v2f z = {0.0f, 0.0f};
    return __builtin_elementwise_max(a, z);
}
__device__ __forceinline__ v2f bcv(const u64 v) {
    return __builtin_bit_cast(v2f, v);
}

__global__ __launch_bounds__(BLOCK) void pnet_kernel(
    const float* __restrict__ x, float* __restrict__ out, int B,
    const float* __restrict__ wstream) {
    const long long row = (long long)blockIdx.x * BLOCK + threadIdx.x;
    if (row >= B) return;

    const u64* W = reinterpret_cast<const u64*>(wstream);

    // ---- load 11 features as 6 overlapping v2f pairs (no packing movs) ----
    const float* pr = x + row * 11;
    const v2f xp01 = *reinterpret_cast<const v2f*>(pr + 0);  // {x0,x1}
    const v2f xp23 = *reinterpret_cast<const v2f*>(pr + 2);  // {h,  k }
    const v2f xp45 = *reinterpret_cast<const v2f*>(pr + 4);  // {f,  x5}
    const v2f xp67 = *reinterpret_cast<const v2f*>(pr + 6);  // {x6, x7}
    const v2f xp89 = *reinterpret_cast<const v2f*>(pr + 8);  // {hd, kd}
    const v2f xp9A = *reinterpret_cast<const v2f*>(pr + 9);  // {kd, fd} fd=hi

    // ---- fu1: off 0, 1 jp, slots {f.L, fd.H} ----
    v2f fu1p;
    {
        v2f a = bcv(W[0]);
        fmaL(a, xp45, W[1]);
        fmaH(a, xp9A, W[2]);
        fu1p = pkmax0(a);
    }
    // ---- fu2: off 3 ----
    v2f fup;
    {
        v2f a = bcv(W[3]);
        fmaL(a, fu1p, W[4]);
        fmaH(a, fu1p, W[5]);
        fup = pkmax0(a);
    }

    // ---- ku1: off 6, 2 jp, stride 5: {k.H, kd.H, fup.L, fup.H} ----
    v2f ku1p[2];
#pragma unroll
    for (int jp = 0; jp < 2; ++jp) {
        const int q = 6 + jp*5;
        v2f a = bcv(W[q]);
        fmaH(a, xp23, W[q+1]);
        fmaH(a, xp89, W[q+2]);
        fmaL(a, fup,  W[q+3]);
        fmaH(a, fup,  W[q+4]);
        ku1p[jp] = pkmax0(a);
    }
    // ---- ku2: off 16, 2 jp, stride 5 ----
    v2f kup[2];
#pragma unroll
    for (int jp = 0; jp < 2; ++jp) {
        const int q = 16 + jp*5;
        v2f a = bcv(W[q]);
        fmaL(a, ku1p[0], W[q+1]);
        fmaH(a, ku1p[0], W[q+2]);
        fmaL(a, ku1p[1], W[q+3]);
        fmaH(a, ku1p[1], W[q+4]);
        kup[jp] = pkmax0(a);
    }

    // ---- hu1: off 26, 3 jp, stride 7: {h.L, hd.L, kup0.L/H, kup1.L/H} ----
    v2f hu1p[3];
#pragma unroll
    for (int jp = 0; jp < 3; ++jp) {
        const int q = 26 + jp*7;
        v2f a = bcv(W[q]);
        fmaL(a, xp23,   W[q+1]);
        fmaL(a, xp89,   W[q+2]);
        fmaL(a, kup[0], W[q+3]);
        fmaH(a, kup[0], W[q+4]);
        fmaL(a, kup[1], W[q+5]);
        fmaH(a, kup[1], W[q+6]);
        hu1p[jp] = pkmax0(a);
    }
    // ---- hu2: off 47, 3 jp, stride 7 ----
    v2f hup[3];
#pragma unroll
    for (int jp = 0; jp < 3; ++jp) {
        const int q = 47 + jp*7;
        v2f a = bcv(W[q]);
        fmaL(a, hu1p[0], W[q+1]);
        fmaH(a, hu1p[0], W[q+2]);
        fmaL(a, hu1p[1], W[q+3]);
        fmaH(a, hu1p[1], W[q+4]);
        fmaL(a, hu1p[2], W[q+5]);
        fmaH(a, hu1p[2], W[q+6]);
        hup[jp] = pkmax0(a);
    }

    // ---- md1: off 68, 8 jp, stride 12: {x0.L,x1.H,x5.H,x6.L,x7.H, hup L/H} ----
    v2f m1[8];
#pragma unroll
    for (int jp = 0; jp < 8; ++jp) {
        const int q = 68 + jp*12;
        v2f a = bcv(W[q]);
        fmaL(a, xp01,   W[q+1]);
        fmaH(a, xp01,   W[q+2]);
        fmaH(a, xp45,   W[q+3]);
        fmaL(a, xp67,   W[q+4]);
        fmaH(a, xp67,   W[q+5]);
        fmaL(a, hup[0], W[q+6]);
        fmaH(a, hup[0], W[q+7]);
        fmaL(a, hup[1], W[q+8]);
        fmaH(a, hup[1], W[q+9]);
        fmaL(a, hup[2], W[q+10]);
        fmaH(a, hup[2], W[q+11]);
        m1[jp] = pkmax0(a);
    }
    // ---- md2: off 164, 8 jp, stride 17 ----
    v2f m2[8];
#pragma unroll
    for (int jp = 0; jp < 8; ++jp) {
        const int q = 164 + jp*17;
        v2f a = bcv(W[q]);
#pragma unroll
        for (int p = 0; p < 8; ++p) {
            fmaL(a, m1[p], W[q + 1 + 2*p]);
            fmaH(a, m1[p], W[q + 2 + 2*p]);
        }
        m2[jp] = pkmax0(a);
    }
    // ---- md3: off 300, 3 jp, stride 17 ----
    v2f m3[3];
#pragma unroll
    for (int jp = 0; jp < 3; ++jp) {
        const int q = 300 + jp*17;
        v2f a = bcv(W[q]);
#pragma unroll
        for (int p = 0; p < 8; ++p) {
            fmaL(a, m2[p], W[q + 1 + 2*p]);
            fmaH(a, m2[p], W[q + 2 + 2*p]);
        }
        m3[jp] = pkmax0(a);
    }

    // ---- hd1: off 351, 2 jp, stride 7 ----
    v2f d1[2];
#pragma unroll
    for (int jp = 0; jp < 2; ++jp) {
        const int q = 351 + jp*7;
        v2f a = bcv(W[q]);
        fmaL(a, m3[0], W[q+1]);
        fmaH(a, m3[0], W[q+2]);
        fmaL(a, m3[1], W[q+3]);
        fmaH(a, m3[1], W[q+4]);
        fmaL(a, m3[2], W[q+5]);
        fmaH(a, m3[2], W[q+6]);
        d1[jp] = pkmax0(a);
    }
    // ---- hd2: off 365, 2 jp, stride 5 ----
    v2f d2[2];
#pragma unroll
    for (int jp = 0; jp < 2; ++jp) {
        const int q = 365 + jp*5;
        v2f a = bcv(W[q]);
        fmaL(a, d1[0], W[q+1]);
        fmaH(a, d1[0], W[q+2]);
        fmaL(a, d1[1], W[q+3]);
        fmaH(a, d1[1], W[q+4]);
        d2[jp] = pkmax0(a);
    }

    // ---- kd1: off 375, 1 jp ----
    v2f e1;
    {
        v2f a = bcv(W[375]);
        fmaL(a, d2[0], W[376]);
        fmaH(a, d2[0], W[377]);
        fmaL(a, d2[1], W[378]);
        fmaH(a, d2[1], W[379]);
        e1 = pkmax0(a);
    }
    // ---- kd2: off 380 ----
    v2f e2;
    {
        v2f a = bcv(W[380]);
        fmaL(a, e1, W[381]);
        fmaH(a, e1, W[382]);
        e2 = pkmax0(a);
    }

    // ---- ha1: off 383, 2 jp, stride 9: {h.L, hd.L, m3 L/H x3} ----
    v2f g[2];
#pragma unroll
    for (int jp = 0; jp < 2; ++jp) {
        const int q = 383 + jp*9;
        v2f a = bcv(W[q]);
        fmaL(a, xp23,  W[q+1]);
        fmaL(a, xp89,  W[q+2]);
        fmaL(a, m3[0], W[q+3]);
        fmaH(a, m3[0], W[q+4]);
        fmaL(a, m3[1], W[q+5]);
        fmaH(a, m3[1], W[q+6]);
        fmaL(a, m3[2], W[q+7]);
        fmaH(a, m3[2], W[q+8]);
        g[jp] = pkmax0(a);
    }
    // ---- ha2: head at float off 802 ----
    float h_act = wstream[802];
    h_act = __builtin_fmaf(g[0].x, wstream[803], h_act);
    h_act = __builtin_fmaf(g[0].y, wstream[804], h_act);
    h_act = __builtin_fmaf(g[1].x, wstream[805], h_act);
    h_act = __builtin_fmaf(g[1].y, wstream[806], h_act);

    // ---- ka1: off 404, 2 jp, stride 7: {k.H, kd.H, d2 L/H x2} ----
    v2f q2[2];
#pragma unroll
    for (int jp = 0; jp < 2; ++jp) {
        const int q = 404 + jp*7;
        v2f a = bcv(W[q]);
        fmaH(a, xp23,  W[q+1]);
        fmaH(a, xp89,  W[q+2]);
        fmaL(a, d2[0], W[q+3]);
        fmaH(a, d2[0], W[q+4]);
        fmaL(a, d2[1], W[q+5]);
        fmaH(a, d2[1], W[q+6]);
        q2[jp] = pkmax0(a);
    }
    // ---- ka2: head at float off 836 ----
    float k_act = wstream[836];
    k_act = __builtin_fmaf(q2[0].x, wstream[837], k_act);
    k_act = __builtin_fmaf(q2[0].y, wstream[838], k_act);
    k_act = __builtin_fmaf(q2[1].x, wstream[839], k_act);
    k_act = __builtin_fmaf(q2[1].y, wstream[840], k_act);

    // ---- fa1: off 421, 2 jp, stride 5: {f.L, fd.H, e2.L, e2.H} ----
    v2f r[2];
#pragma unroll
    for (int jp = 0; jp < 2; ++jp) {
        const int q = 421 + jp*5;
        v2f a = bcv(W[q]);
        fmaL(a, xp45, W[q+1]);
        fmaH(a, xp9A, W[q+2]);
        fmaL(a, e2,   W[q+3]);
        fmaH(a, e2,   W[q+4]);
        r[jp] = pkmax0(a);
    }
    // ---- fa2: head at float off 862 ----
    float f_act = wstream[862];
    f_act = __builtin_fmaf(r[0].x, wstream[863], f_act);
    f_act = __builtin_fmaf(r[0].y, wstream[864], f_act);
    f_act = __builtin_fmaf(r[1].x, wstream[865], f_act);
    f_act = __builtin_fmaf(r[1].y, wstream[866], f_act);

    // ---- store ----
    float* po = out + row * 3;
    po[0] = h_act;
    po[1] = f_act;
    po[2] = k_act;
}

extern "C" void kernel_launch(void* const* d_in, const int* in_sizes, int n_in,
                              void* d_out, int out_size, void* d_ws, size_t ws_size,
                              hipStream_t stream) {
    const float* x = (const float*)d_in[0];
    float* out = (float*)d_out;
    const int B = in_sizes[0] / 11;

    WPtrs P;
    for (int i = 0; i < 19; ++i) {
        P.w[i] = (const float*)d_in[1 + 2*i];
        P.b[i] = (const float*)d_in[2 + 2*i];
    }

    float* ws = (float*)d_ws;
    prep_kernel<<<19, 32, 0, stream>>>(P, ws);   // 3.5KB stream, ~2 us

    const int blocks = (int)(((long long)B + BLOCK - 1) / BLOCK);
    pnet_kernel<<<blocks, BLOCK, 0, stream>>>(x, out, B, ws);
}